// Round 1
// baseline (83.896 us; speedup 1.0000x reference)
//
#include <hip/hip_runtime.h>
#include <math.h>

#define NG 2048
#define IMG_W 128
#define IMG_H 128
#define NPIX (IMG_W * IMG_H)
#define ALPHA_MIN (1.0f / 255.0f)
#define NSEG 16               // z-segments per tile (one per wave)
#define SEG (NG / NSEG)       // 128 gaussians per segment = 2 chunks of 64

// Session knowledge: harness base ~57us (R4/R5); cooperative launch ~30us
// as a graph node (R3); device-scope fences ~40us at wave scale (R4/R5) ->
// kernel-boundary coherence only. R10: work reduction neutral -> residual is
// per-kernel fixed cost (dispatch + SCLK ramp). R11: 2 kernels, 512 total
// workgroups. R12 (this round): fuse to ONE kernel — each block redundantly
// z-sorts all 2048 gaussians in LDS (u64 bitonic, stable via (zbits<<32)|idx
// key) and projects them (f64, op-order identical to the old prep kernel ->
// bit-identical AoS/radii), then renders its tile from LDS. Removes one
// dispatch fixed cost AND the prep->render full-grid drain.
//
// LDS: keys 16KB (reused as the segment-merge buffer post-render) +
// SoA float4 AoS 3x32KB = 112KB total -> 1 block/CU (fine: 256 blocks on
// 256 CUs was already 1/CU).

__global__ void __launch_bounds__(1024) fused_kernel(const float* __restrict__ means,
                                                     const float* __restrict__ colors,
                                                     const float* __restrict__ opac,
                                                     const float* __restrict__ cov3,
                                                     const float* __restrict__ bgp,
                                                     float* __restrict__ out,
                                                     float* __restrict__ radii_out) {
    __shared__ unsigned long long keys[NG];          // 16 KB; aliased as part[] later
    __shared__ float4 s_a0[NG], s_a1[NG], s_a2[NG];  // 96 KB z-sorted params:
    // a0 = (px, py, Lc, A)  a1 = (B, C, op, cr)  a2 = (cg, cb, BoA, BoC)

    const int t = threadIdx.x;
    const int lane = t & 63;
    const int wave = t >> 6;
    const int b = blockIdx.x;

    // ---- phase 1: load stable sort keys (z asc, ties by index) ------------
    for (int k = t; k < NG; k += 1024) {
        const float z = means[k * 3 + 2];  // z in (2,6): positive -> bits monotone
        keys[k] = ((unsigned long long)__float_as_uint(z) << 32) | (unsigned)k;
    }
    __syncthreads();

    // ---- phase 2: bitonic sort of 2048 u64 keys ---------------------------
    // Wave-local passes (j < 128, pairs inside this wave's 128-elem chunk):
    // no __syncthreads needed — DS ops from one wave execute in order, the
    // asm memory clobber only stops compiler caching/reordering.
    const int chunk = wave * 128;
#define LOCAL_PASS(K, J)                                                     \
    {                                                                        \
        const int il = ((lane & ~((J) - 1)) << 1) | (lane & ((J) - 1));      \
        const int i = chunk + il;                                            \
        const unsigned long long a0_ = keys[i];                              \
        const unsigned long long a1_ = keys[i + (J)];                        \
        const bool up = ((i & (K)) == 0);                                    \
        const bool sw = (a0_ > a1_) == up;                                   \
        keys[i] = sw ? a1_ : a0_;                                            \
        keys[i + (J)] = sw ? a0_ : a1_;                                      \
        asm volatile("" ::: "memory");                                       \
    }

#pragma unroll
    for (int k = 2; k <= 128; k <<= 1) {
#pragma unroll
        for (int j = k >> 1; j >= 1; j >>= 1) LOCAL_PASS(k, j)
    }
    __syncthreads();
#pragma unroll
    for (int k = 256; k <= 2048; k <<= 1) {
#pragma unroll
        for (int j = k >> 1; j >= 128; j >>= 1) {  // cross-wave passes
            const int i = ((t & ~(j - 1)) << 1) | (t & (j - 1));
            const unsigned long long a0_ = keys[i];
            const unsigned long long a1_ = keys[i + j];
            const bool up = ((i & k) == 0);
            const bool sw = (a0_ > a1_) == up;
            keys[i] = sw ? a1_ : a0_;
            keys[i + j] = sw ? a0_ : a1_;
            __syncthreads();
        }
#pragma unroll
        for (int j = 64; j >= 1; j >>= 1) LOCAL_PASS(k, j)
        __syncthreads();
    }
#undef LOCAL_PASS

    // ---- phase 3: projection/conic (f64 path, op-order identical to the ---
    // old prep kernel -> bit-identical f32 AoS + radii) + sorted scatter.
    for (int r = t; r < NG; r += 1024) {
        const int i = (int)(keys[r] & 0xffffffffULL);
        const double x = means[i * 3 + 0];
        const double y = means[i * 3 + 1];
        const double z = means[i * 3 + 2];
        const double inv_z = 1.0 / z;
        const double fx = 128.0, fy = 128.0, lim = 0.65;  // W/(2*tanfov), 1.3*tanfov
        const double px = fx * x * inv_z + 64.0;
        const double py = fy * y * inv_z + 64.0;
        double tx = x * inv_z; tx = fmin(fmax(tx, -lim), lim); tx *= z;
        double ty = y * inv_z; ty = fmin(fmax(ty, -lim), lim); ty *= z;
        const double xx = cov3[i * 6 + 0], xy = cov3[i * 6 + 1], xz = cov3[i * 6 + 2];
        const double yy = cov3[i * 6 + 3], yz = cov3[i * 6 + 4], zz = cov3[i * 6 + 5];
        const double J00 = fx * inv_z, J02 = -fx * tx * inv_z * inv_z;
        const double J11 = fy * inv_z, J12 = -fy * ty * inv_z * inv_z;
        const double M00 = J00 * xx + J02 * xz;
        const double M01 = J00 * xy + J02 * yz;
        const double M02 = J00 * xz + J02 * zz;
        const double M11 = J11 * yy + J12 * yz;
        const double M12 = J11 * yz + J12 * zz;
        const double a  = M00 * J00 + M02 * J02 + 0.3;
        const double bb = M01 * J11 + M02 * J12;  // cov2[0,1]
        const double c  = M11 * J11 + M12 * J12 + 0.3;
        const double det = a * c - bb * bb;
        const bool valid = (z > 0.2) && (det > 0.0);

        // f32 params feeding image/cull (ref is f32 too)
        const float af = (float)a, bf = (float)bb, cf = (float)c;
        const float inv_det_f = 1.0f / (float)det;
        const float op = opac[i];
        // Cull: keep (gaussian,tile) iff min over tile rect of
        // 0.5 d^T Sigma^-1 d <= Lc = ln(255*op)+0.05 (margin >> f32 error).
        float Lc = -1.0f;
        if (valid) {
            const float L = logf(255.0f * op);
            Lc = (L > 0.0f) ? (L + 0.05f) : -1.0f;
        }
        s_a0[r] = make_float4((float)px, (float)py, Lc, cf * inv_det_f);
        s_a1[r] = make_float4(-bf * inv_det_f, af * inv_det_f, op,
                              colors[i * 3 + 0]);
        s_a2[r] = make_float4(colors[i * 3 + 1], colors[i * 3 + 2],
                              -bf / cf, -bf / af);  // B/A, B/C

        if ((i >> 3) == b) {  // each block writes its own 8 radii (f64 ceil path)
            const double mid = 0.5 * (a + c);
            const double lam1 = mid + sqrt(fmax(0.1, mid * mid - det));
            radii_out[i] = valid ? (float)ceil(3.0 * sqrt(lam1)) : 0.0f;
        }
    }
    __syncthreads();

    // ---- phase 4: render this block's 8x8 tile from LDS -------------------
    // Wave w composites z-segment [w*128, w*128+128) in 2 chunks of 64.
    // Exact ellipse-vs-rect cull per lane, ballot, readlane hit loop.
    const int tile = b;
    const int tile_x = (tile & 15) * 8;
    const int tile_y = (tile >> 4) * 8;
    const float pxf = (float)(tile_x + (lane & 7));
    const float pyf = (float)(tile_y + (lane >> 3));
    const float tx0 = (float)tile_x, tx1 = (float)(tile_x + 7);
    const float ty0 = (float)tile_y, ty1 = (float)(tile_y + 7);

    float T = 1.0f, accr = 0.0f, accg = 0.0f, accb = 0.0f;

#define RL(x, jj) __int_as_float(__builtin_amdgcn_readlane(__float_as_int(x), jj))
#pragma unroll
    for (int c = 0; c < SEG / 64; ++c) {
        const int g = wave * SEG + c * 64 + lane;
        const float4 a0 = s_a0[g];
        const float4 a1 = s_a1[g];
        const float4 a2 = s_a2[g];

        // exact ellipse-vs-rect cull (lane-parallel, one gaussian/lane)
        const float lx = a0.x - tx1, hx = a0.x - tx0;
        const float ly = a0.y - ty1, hy = a0.y - ty0;
        const float hA = 0.5f * a0.w, hC = 0.5f * a1.y;
        const float Bq = a1.x, BoA = a2.z, BoC = a2.w;
        const bool inside = (lx <= 0.0f) & (hx >= 0.0f) & (ly <= 0.0f) & (hy >= 0.0f);
        const float dy1 = fminf(fmaxf(-BoC * lx, ly), hy);
        const float q1  = hA * lx * lx + Bq * lx * dy1 + hC * dy1 * dy1;
        const float dy2 = fminf(fmaxf(-BoC * hx, ly), hy);
        const float q2  = hA * hx * hx + Bq * hx * dy2 + hC * dy2 * dy2;
        const float dx3 = fminf(fmaxf(-BoA * ly, lx), hx);
        const float q3  = hC * ly * ly + Bq * dx3 * ly + hA * dx3 * dx3;
        const float dx4 = fminf(fmaxf(-BoA * hy, lx), hx);
        const float q4  = hC * hy * hy + Bq * dx4 * hy + hA * dx4 * dx4;
        float qm = fminf(fminf(q1, q2), fminf(q3, q4));
        if (inside) qm = 0.0f;
        unsigned long long m = __ballot(qm <= a0.z);   // q_min <= Lc

        while (m) {
            const int j = __builtin_ctzll(m);
            m &= (m - 1);
            const float cx = RL(a0.x, j), cy = RL(a0.y, j);
            const float A = RL(a0.w, j), B = RL(a1.x, j), C = RL(a1.y, j);
            const float op = RL(a1.z, j);
            const float cr = RL(a1.w, j), cg = RL(a2.x, j), cb = RL(a2.y, j);
            const float dx = cx - pxf, dy = cy - pyf;
            const float power = -0.5f * (A * dx * dx + C * dy * dy) - B * dx * dy;
            const float alpha = fminf(0.99f, op * __expf(power));
            const bool keep = (power <= 0.0f) & (alpha >= ALPHA_MIN);
            const float ae = keep ? alpha : 0.0f;
            const float w = ae * T;
            accr = fmaf(w, cr, accr);
            accg = fmaf(w, cg, accg);
            accb = fmaf(w, cb, accb);
            T = fmaf(-ae, T, T);
        }
    }
#undef RL

    // merge the 16 z-segments, front to back (exact reassociation):
    //   img = sum_s (prod_{s'<s} T_s') * acc_s ,  T = prod_s T_s.
    // part[] aliases keys[] — safe: last keys read was before the phase-3
    // barrier, so all reads precede any part write.
    float (*part)[4][64] = reinterpret_cast<float (*)[4][64]>(keys);
    part[wave][0][lane] = accr;
    part[wave][1][lane] = accg;
    part[wave][2][lane] = accb;
    part[wave][3][lane] = T;
    __syncthreads();
    if (wave == 0) {
        float R = part[0][0][lane], G = part[0][1][lane], Bc = part[0][2][lane];
        float Tt = part[0][3][lane];
#pragma unroll
        for (int s = 1; s < NSEG; ++s) {
            R  = fmaf(Tt, part[s][0][lane], R);
            G  = fmaf(Tt, part[s][1][lane], G);
            Bc = fmaf(Tt, part[s][2][lane], Bc);
            Tt *= part[s][3][lane];
        }
        const int pix = (tile_y + (lane >> 3)) * IMG_W + tile_x + (lane & 7);
        out[pix]            = fmaf(Tt, bgp[0], R);
        out[pix + NPIX]     = fmaf(Tt, bgp[1], G);
        out[pix + 2 * NPIX] = fmaf(Tt, bgp[2], Bc);
    }
}

// ---------------------------------------------------------------------------
extern "C" void kernel_launch(void* const* d_in, const int* in_sizes, int n_in,
                              void* d_out, int out_size, void* d_ws, size_t ws_size,
                              hipStream_t stream) {
    const float* means  = (const float*)d_in[0];  // (N,3)
    const float* colors = (const float*)d_in[1];  // (N,3)
    const float* opac   = (const float*)d_in[2];  // (N,1)
    const float* cov3   = (const float*)d_in[3];  // (N,6)
    const float* bg     = (const float*)d_in[4];  // (3,)
    float* out = (float*)d_out;  // img (3*128*128) then radii (2048) as float

    fused_kernel<<<256, 1024, 0, stream>>>(means, colors, opac, cov3, bg,
                                           out, out + 3 * NPIX);
}

// Round 2
// 70.292 us; speedup vs baseline: 1.1935x; 1.1935x over previous
//
#include <hip/hip_runtime.h>
#include <math.h>

#define NG 2048
#define IMG_W 128
#define IMG_H 128
#define NPIX (IMG_W * IMG_H)
#define ALPHA_MIN (1.0f / 255.0f)
#define NSEG 16               // survivor chunks per tile (one per wave)

// Session knowledge: harness base ~57us (R4/R5); cooperative launch ~30us as a
// graph node (R3); device-scope fences ~40us (R4/R5). R10: work reduction
// neutral -> residual is per-kernel fixed cost. R11 (71.5us): 2 kernels.
// R12 (83.9us REGRESSION): fusion w/ per-block 2048-key bitonic sort — the
// sort alone is ~5-7us/block (2.1MB LDS traffic, 15 16-wave barriers) and
// swamped the ~5-8us dispatch+drain savings. Lesson: fusion is right, full
// sort is wrong.
// R13 (this): cull FIRST, sort only survivors. Per tile only ~40-120 of 2048
// gaussians pass the exact ellipse-vs-rect cull (all others contribute
// exactly 0 — same test the passing kernels already rely on). Projection
// doesn't need sorted order -> project to AoS indexed by original i, cull,
// compact via ballot+LDS-atomic, rank-sort ~100 survivor keys by broadcast
// rank-count (~10K comparisons vs 135K bitonic element-ops), composite in
// 16 contiguous z-chunks with the existing exact merge. 4 barriers total.
// Per-pixel composite values identical to R11 (same survivor set, same
// z-order, same alpha math); only T-chain reassociation boundaries move.
//
// LDS: zkeys 16KB (aliased as part[] in the merge) + survKeys 16KB +
// sortedId 8KB + SoA float4 AoS 96KB = 136KB -> 1 block/CU (was already).

__global__ void __launch_bounds__(1024) fused_kernel(const float* __restrict__ means,
                                                     const float* __restrict__ colors,
                                                     const float* __restrict__ opac,
                                                     const float* __restrict__ cov3,
                                                     const float* __restrict__ bgp,
                                                     float* __restrict__ out,
                                                     float* __restrict__ radii_out) {
    __shared__ unsigned long long zkeys[NG];          // 16 KB, unsorted (by i); aliased as part[]
    __shared__ unsigned long long survKeys[NG];       // 16 KB, compacted survivors (unordered)
    __shared__ unsigned int sortedId[NG];             // 8 KB, survivor gaussian idx by z-rank
    __shared__ float4 s_a0[NG], s_a1[NG], s_a2[NG];   // 96 KB params INDEXED BY ORIGINAL i:
    // a0 = (px, py, Lc, A)  a1 = (B, C, op, cr)  a2 = (cg, cb, BoA, BoC)
    __shared__ int nsurv;

    const int t = threadIdx.x;
    const int lane = t & 63;
    const int wave = t >> 6;
    const int b = blockIdx.x;

    if (t == 0) nsurv = 0;

    // ---- phase P: project all 2048 (f64 path, op-order identical to the ---
    // old prep kernel -> bit-identical f32 AoS + radii). AoS by original i.
    for (int i = t; i < NG; i += 1024) {
        const float zf = means[i * 3 + 2];  // z in (2,6): positive -> bits monotone
        zkeys[i] = ((unsigned long long)__float_as_uint(zf) << 32) | (unsigned)i;

        const double x = means[i * 3 + 0];
        const double y = means[i * 3 + 1];
        const double z = (double)zf;
        const double inv_z = 1.0 / z;
        const double fx = 128.0, fy = 128.0, lim = 0.65;  // W/(2*tanfov), 1.3*tanfov
        const double px = fx * x * inv_z + 64.0;
        const double py = fy * y * inv_z + 64.0;
        double tx = x * inv_z; tx = fmin(fmax(tx, -lim), lim); tx *= z;
        double ty = y * inv_z; ty = fmin(fmax(ty, -lim), lim); ty *= z;
        const double xx = cov3[i * 6 + 0], xy = cov3[i * 6 + 1], xz = cov3[i * 6 + 2];
        const double yy = cov3[i * 6 + 3], yz = cov3[i * 6 + 4], zz = cov3[i * 6 + 5];
        const double J00 = fx * inv_z, J02 = -fx * tx * inv_z * inv_z;
        const double J11 = fy * inv_z, J12 = -fy * ty * inv_z * inv_z;
        const double M00 = J00 * xx + J02 * xz;
        const double M01 = J00 * xy + J02 * yz;
        const double M02 = J00 * xz + J02 * zz;
        const double M11 = J11 * yy + J12 * yz;
        const double M12 = J11 * yz + J12 * zz;
        const double a  = M00 * J00 + M02 * J02 + 0.3;
        const double bb = M01 * J11 + M02 * J12;  // cov2[0,1]
        const double c  = M11 * J11 + M12 * J12 + 0.3;
        const double det = a * c - bb * bb;
        const bool valid = (z > 0.2) && (det > 0.0);

        // f32 params feeding image/cull (ref is f32 too)
        const float af = (float)a, bf = (float)bb, cf = (float)c;
        const float inv_det_f = 1.0f / (float)det;
        const float op = opac[i];
        // Cull: keep (gaussian,tile) iff min over tile rect of
        // 0.5 d^T Sigma^-1 d <= Lc = ln(255*op)+0.05 (margin >> f32 error).
        float Lc = -1.0f;
        if (valid) {
            const float L = logf(255.0f * op);
            Lc = (L > 0.0f) ? (L + 0.05f) : -1.0f;
        }
        s_a0[i] = make_float4((float)px, (float)py, Lc, cf * inv_det_f);
        s_a1[i] = make_float4(-bf * inv_det_f, af * inv_det_f, op,
                              colors[i * 3 + 0]);
        s_a2[i] = make_float4(colors[i * 3 + 1], colors[i * 3 + 2],
                              -bf / cf, -bf / af);  // B/A, B/C

        if ((i >> 3) == b) {  // each block writes its own 8 radii (f64 ceil path)
            const double mid = 0.5 * (a + c);
            const double lam1 = mid + sqrt(fmax(0.1, mid * mid - det));
            radii_out[i] = valid ? (float)ceil(3.0 * sqrt(lam1)) : 0.0f;
        }
    }
    __syncthreads();

    // ---- phase C: exact ellipse-vs-rect cull of all 2048; compact ---------
    // survivor keys (unordered) via ballot + per-wave LDS-atomic append.
    const int tile_x = (b & 15) * 8;
    const int tile_y = (b >> 4) * 8;
    const float tx0 = (float)tile_x, tx1 = (float)(tile_x + 7);
    const float ty0 = (float)tile_y, ty1 = (float)(tile_y + 7);

#pragma unroll
    for (int c = 0; c < 2; ++c) {
        const int g = wave * 128 + c * 64 + lane;
        const float4 a0 = s_a0[g];
        const float4 a1 = s_a1[g];
        const float4 a2 = s_a2[g];
        const float lx = a0.x - tx1, hx = a0.x - tx0;
        const float ly = a0.y - ty1, hy = a0.y - ty0;
        const float hA = 0.5f * a0.w, hC = 0.5f * a1.y;
        const float Bq = a1.x, BoA = a2.z, BoC = a2.w;
        const bool inside = (lx <= 0.0f) & (hx >= 0.0f) & (ly <= 0.0f) & (hy >= 0.0f);
        const float dy1 = fminf(fmaxf(-BoC * lx, ly), hy);
        const float q1  = hA * lx * lx + Bq * lx * dy1 + hC * dy1 * dy1;
        const float dy2 = fminf(fmaxf(-BoC * hx, ly), hy);
        const float q2  = hA * hx * hx + Bq * hx * dy2 + hC * dy2 * dy2;
        const float dx3 = fminf(fmaxf(-BoA * ly, lx), hx);
        const float q3  = hC * ly * ly + Bq * dx3 * ly + hA * dx3 * dx3;
        const float dx4 = fminf(fmaxf(-BoA * hy, lx), hx);
        const float q4  = hC * hy * hy + Bq * dx4 * hy + hA * dx4 * dx4;
        float qm = fminf(fminf(q1, q2), fminf(q3, q4));
        if (inside) qm = 0.0f;
        const bool hit = (qm <= a0.z);   // q_min <= Lc
        const unsigned long long m = __ballot(hit);
        const int cnt = __popcll(m);
        int base = 0;
        if (lane == 0 && cnt) base = atomicAdd(&nsurv, cnt);
        base = __builtin_amdgcn_readfirstlane(base);
        if (hit) {
            const int pos = __popcll(m & ((1ull << lane) - 1ull));
            survKeys[base + pos] = zkeys[g];
        }
    }
    __syncthreads();

    // ---- phase S: rank-sort the ~40-120 survivors by (z, idx) -------------
    // rank = count of strictly-smaller keys (keys distinct: idx in low bits).
    // Inner loop reads the same LDS word on every thread -> broadcast.
    const int n = nsurv;
    for (int s = t; s < n; s += 1024) {
        const unsigned long long k = survKeys[s];
        int r = 0;
        for (int j = 0; j < n; ++j) r += (survKeys[j] < k) ? 1 : 0;
        sortedId[r] = (unsigned int)(k & 0xffffffffull);
    }
    __syncthreads();

    // ---- phase R: composite. Wave w takes contiguous z-chunk w of the -----
    // sorted survivors (front-to-back within the wave); exact merge below.
    const float pxf = (float)(tile_x + (lane & 7));
    const float pyf = (float)(tile_y + (lane >> 3));
    float T = 1.0f, accr = 0.0f, accg = 0.0f, accb = 0.0f;

    const int cs = (n + NSEG - 1) >> 4;
    const int r0 = wave * cs;
    const int r1 = min(r0 + cs, n);
    for (int r = r0; r < r1; ++r) {
        const unsigned int id = sortedId[r];
        const float4 a0 = s_a0[id];   // broadcast reads (same addr all lanes)
        const float4 a1 = s_a1[id];
        const float4 a2 = s_a2[id];
        const float dx = a0.x - pxf, dy = a0.y - pyf;
        const float power = -0.5f * (a0.w * dx * dx + a1.y * dy * dy) - a1.x * dx * dy;
        const float alpha = fminf(0.99f, a1.z * __expf(power));
        const bool keep = (power <= 0.0f) & (alpha >= ALPHA_MIN);
        const float ae = keep ? alpha : 0.0f;
        const float w = ae * T;
        accr = fmaf(w, a1.w, accr);
        accg = fmaf(w, a2.x, accg);
        accb = fmaf(w, a2.y, accb);
        T = fmaf(-ae, T, T);
    }

    // merge the 16 chunks, front to back (exact reassociation):
    //   img = sum_s (prod_{s'<s} T_s') * acc_s ,  T = prod_s T_s.
    // part[] aliases zkeys[] — safe: last zkeys read was in phase C, two
    // barriers ago.
    float (*part)[4][64] = reinterpret_cast<float (*)[4][64]>(zkeys);
    part[wave][0][lane] = accr;
    part[wave][1][lane] = accg;
    part[wave][2][lane] = accb;
    part[wave][3][lane] = T;
    __syncthreads();
    if (wave == 0) {
        float R = part[0][0][lane], G = part[0][1][lane], Bc = part[0][2][lane];
        float Tt = part[0][3][lane];
#pragma unroll
        for (int s = 1; s < NSEG; ++s) {
            R  = fmaf(Tt, part[s][0][lane], R);
            G  = fmaf(Tt, part[s][1][lane], G);
            Bc = fmaf(Tt, part[s][2][lane], Bc);
            Tt *= part[s][3][lane];
        }
        const int pix = (tile_y + (lane >> 3)) * IMG_W + tile_x + (lane & 7);
        out[pix]            = fmaf(Tt, bgp[0], R);
        out[pix + NPIX]     = fmaf(Tt, bgp[1], G);
        out[pix + 2 * NPIX] = fmaf(Tt, bgp[2], Bc);
    }
}

// ---------------------------------------------------------------------------
extern "C" void kernel_launch(void* const* d_in, const int* in_sizes, int n_in,
                              void* d_out, int out_size, void* d_ws, size_t ws_size,
                              hipStream_t stream) {
    const float* means  = (const float*)d_in[0];  // (N,3)
    const float* colors = (const float*)d_in[1];  // (N,3)
    const float* opac   = (const float*)d_in[2];  // (N,1)
    const float* cov3   = (const float*)d_in[3];  // (N,6)
    const float* bg     = (const float*)d_in[4];  // (3,)
    float* out = (float*)d_out;  // img (3*128*128) then radii (2048) as float

    fused_kernel<<<256, 1024, 0, stream>>>(means, colors, opac, cov3, bg,
                                           out, out + 3 * NPIX);
}

// Round 3
// 69.835 us; speedup vs baseline: 1.2013x; 1.0065x over previous
//
#include <hip/hip_runtime.h>
#include <math.h>

#define NG 2048
#define IMG_W 128
#define IMG_H 128
#define NPIX (IMG_W * IMG_H)
#define ALPHA_MIN (1.0f / 255.0f)
#define NSEG 16               // survivor chunks per tile (one per wave)

// Session knowledge: harness base ~57us (R4/R5); fill/reset memset (268MB,
// 39us @85% HBM) + launch/sync + SCLK ramp form a fixed floor; removing a
// dispatch is worth ~1us (R11 71.5 -> R13 70.3), kernel time maps 1:1 into
// dur_us (R12<->R13: bitonic sort cost 13.6us e2e). R12 (83.9us): full
// per-block bitonic sort — wrong. R13 (70.3us): cull-first, rank-sort ~100
// survivors.
// R14 (this): fuse the cull INTO the projection loop — test with the f32
// conic values still in registers, ballot-append survivors inline. Removes
// one 16-wave barrier, the full 96KB AoS re-read of phase C, and the zkeys
// array (-16KB LDS). Survivor set / sort order / composite math bit-identical
// (atomic append order is canonicalized by the rank-sort, as before).
//
// LDS: survKeys 16KB (aliased as part[] in the merge) + sortedId 8KB +
// SoA float4 AoS 96KB = 120KB -> 1 block/CU (256 blocks on 256 CUs).

__global__ void __launch_bounds__(1024) fused_kernel(const float* __restrict__ means,
                                                     const float* __restrict__ colors,
                                                     const float* __restrict__ opac,
                                                     const float* __restrict__ cov3,
                                                     const float* __restrict__ bgp,
                                                     float* __restrict__ out,
                                                     float* __restrict__ radii_out) {
    __shared__ unsigned long long survKeys[NG];       // 16 KB, compacted survivors (unordered)
    __shared__ unsigned int sortedId[NG];             // 8 KB, survivor gaussian idx by z-rank
    __shared__ float4 s_a0[NG], s_a1[NG], s_a2[NG];   // 96 KB params INDEXED BY ORIGINAL i:
    // a0 = (px, py, Lc, A)  a1 = (B, C, op, cr)  a2 = (cg, cb, BoA, BoC)
    __shared__ int nsurv;

    const int t = threadIdx.x;
    const int lane = t & 63;
    const int wave = t >> 6;
    const int b = blockIdx.x;

    if (t == 0) nsurv = 0;
    // nsurv=0 visible before any atomicAdd: wave-uniform path, first atomic
    // happens after this wave's own ds write (per-wave ordering) and other
    // waves' atomics only bump a counter that t==0 initialized at t=0 of
    // wave 0 — guard with a cheap barrier to be safe across waves:
    __syncthreads();

    const int tile_x = (b & 15) * 8;
    const int tile_y = (b >> 4) * 8;
    const float tx0 = (float)tile_x, tx1 = (float)(tile_x + 7);
    const float ty0 = (float)tile_y, ty1 = (float)(tile_y + 7);

    // ---- phase P+C: project all 2048 (f64 path, op-order identical to the
    // old prep kernel -> bit-identical f32 AoS + radii), AoS by original i,
    // and cull inline with the f32 values still in registers; ballot-append
    // survivor keys (z-bits, idx).
    for (int i = t; i < NG; i += 1024) {
        const float zf = means[i * 3 + 2];  // z in (2,6): positive -> bits monotone

        const double x = means[i * 3 + 0];
        const double y = means[i * 3 + 1];
        const double z = (double)zf;
        const double inv_z = 1.0 / z;
        const double fx = 128.0, fy = 128.0, lim = 0.65;  // W/(2*tanfov), 1.3*tanfov
        const double px = fx * x * inv_z + 64.0;
        const double py = fy * y * inv_z + 64.0;
        double txc = x * inv_z; txc = fmin(fmax(txc, -lim), lim); txc *= z;
        double tyc = y * inv_z; tyc = fmin(fmax(tyc, -lim), lim); tyc *= z;
        const double xx = cov3[i * 6 + 0], xy = cov3[i * 6 + 1], xz = cov3[i * 6 + 2];
        const double yy = cov3[i * 6 + 3], yz = cov3[i * 6 + 4], zz = cov3[i * 6 + 5];
        const double J00 = fx * inv_z, J02 = -fx * txc * inv_z * inv_z;
        const double J11 = fy * inv_z, J12 = -fy * tyc * inv_z * inv_z;
        const double M00 = J00 * xx + J02 * xz;
        const double M01 = J00 * xy + J02 * yz;
        const double M02 = J00 * xz + J02 * zz;
        const double M11 = J11 * yy + J12 * yz;
        const double M12 = J11 * yz + J12 * zz;
        const double a  = M00 * J00 + M02 * J02 + 0.3;
        const double bb = M01 * J11 + M02 * J12;  // cov2[0,1]
        const double c  = M11 * J11 + M12 * J12 + 0.3;
        const double det = a * c - bb * bb;
        const bool valid = (z > 0.2) && (det > 0.0);

        // f32 params feeding image/cull (ref is f32 too)
        const float af = (float)a, bf = (float)bb, cf = (float)c;
        const float inv_det_f = 1.0f / (float)det;
        const float op = opac[i];
        // Cull: keep (gaussian,tile) iff min over tile rect of
        // 0.5 d^T Sigma^-1 d <= Lc = ln(255*op)+0.05 (margin >> f32 error).
        float Lc = -1.0f;
        if (valid) {
            const float L = logf(255.0f * op);
            Lc = (L > 0.0f) ? (L + 0.05f) : -1.0f;
        }
        const float pxF = (float)px, pyF = (float)py;
        const float Af  = cf * inv_det_f;            // a0.w
        const float Bf  = -bf * inv_det_f;           // a1.x
        const float Cf  = af * inv_det_f;            // a1.y
        const float BoA = -bf / cf;                  // a2.z
        const float BoC = -bf / af;                  // a2.w

        s_a0[i] = make_float4(pxF, pyF, Lc, Af);
        s_a1[i] = make_float4(Bf, Cf, op, colors[i * 3 + 0]);
        s_a2[i] = make_float4(colors[i * 3 + 1], colors[i * 3 + 2], BoA, BoC);

        if ((i >> 3) == b) {  // each block writes its own 8 radii (f64 ceil path)
            const double mid = 0.5 * (a + c);
            const double lam1 = mid + sqrt(fmax(0.1, mid * mid - det));
            radii_out[i] = valid ? (float)ceil(3.0 * sqrt(lam1)) : 0.0f;
        }

        // exact ellipse-vs-rect cull — IDENTICAL expressions/values to the
        // phase-C version (same f32 registers the AoS stores).
        const float lx = pxF - tx1, hx = pxF - tx0;
        const float ly = pyF - ty1, hy = pyF - ty0;
        const float hA = 0.5f * Af, hC = 0.5f * Cf;
        const float Bq = Bf;
        const bool inside = (lx <= 0.0f) & (hx >= 0.0f) & (ly <= 0.0f) & (hy >= 0.0f);
        const float dy1 = fminf(fmaxf(-BoC * lx, ly), hy);
        const float q1  = hA * lx * lx + Bq * lx * dy1 + hC * dy1 * dy1;
        const float dy2 = fminf(fmaxf(-BoC * hx, ly), hy);
        const float q2  = hA * hx * hx + Bq * hx * dy2 + hC * dy2 * dy2;
        const float dx3 = fminf(fmaxf(-BoA * ly, lx), hx);
        const float q3  = hC * ly * ly + Bq * dx3 * ly + hA * dx3 * dx3;
        const float dx4 = fminf(fmaxf(-BoA * hy, lx), hx);
        const float q4  = hC * hy * hy + Bq * dx4 * hy + hA * dx4 * dx4;
        float qm = fminf(fminf(q1, q2), fminf(q3, q4));
        if (inside) qm = 0.0f;
        const bool hit = (qm <= Lc);   // q_min <= Lc

        const unsigned long long m = __ballot(hit);
        const int cnt = __popcll(m);
        int base = 0;
        if (lane == 0 && cnt) base = atomicAdd(&nsurv, cnt);
        base = __builtin_amdgcn_readfirstlane(base);
        if (hit) {
            const int pos = __popcll(m & ((1ull << lane) - 1ull));
            survKeys[base + pos] =
                ((unsigned long long)__float_as_uint(zf) << 32) | (unsigned)i;
        }
    }
    __syncthreads();

    // ---- phase S: rank-sort the ~40-120 survivors by (z, idx) -------------
    // rank = count of strictly-smaller keys (keys distinct: idx in low bits).
    // Inner loop reads the same LDS word on every thread -> broadcast.
    const int n = nsurv;
    for (int s = t; s < n; s += 1024) {
        const unsigned long long k = survKeys[s];
        int r = 0;
        for (int j = 0; j < n; ++j) r += (survKeys[j] < k) ? 1 : 0;
        sortedId[r] = (unsigned int)(k & 0xffffffffull);
    }
    __syncthreads();

    // ---- phase R: composite. Wave w takes contiguous z-chunk w of the -----
    // sorted survivors (front-to-back within the wave); exact merge below.
    const float pxf = (float)(tile_x + (lane & 7));
    const float pyf = (float)(tile_y + (lane >> 3));
    float T = 1.0f, accr = 0.0f, accg = 0.0f, accb = 0.0f;

    const int cs = (n + NSEG - 1) >> 4;
    const int r0 = wave * cs;
    const int r1 = min(r0 + cs, n);
    for (int r = r0; r < r1; ++r) {
        const unsigned int id = sortedId[r];
        const float4 a0 = s_a0[id];   // broadcast reads (same addr all lanes)
        const float4 a1 = s_a1[id];
        const float4 a2 = s_a2[id];
        const float dx = a0.x - pxf, dy = a0.y - pyf;
        const float power = -0.5f * (a0.w * dx * dx + a1.y * dy * dy) - a1.x * dx * dy;
        const float alpha = fminf(0.99f, a1.z * __expf(power));
        const bool keep = (power <= 0.0f) & (alpha >= ALPHA_MIN);
        const float ae = keep ? alpha : 0.0f;
        const float w = ae * T;
        accr = fmaf(w, a1.w, accr);
        accg = fmaf(w, a2.x, accg);
        accb = fmaf(w, a2.y, accb);
        T = fmaf(-ae, T, T);
    }

    // merge the 16 chunks, front to back (exact reassociation):
    //   img = sum_s (prod_{s'<s} T_s') * acc_s ,  T = prod_s T_s.
    // part[] aliases survKeys[] — safe: last survKeys read was in phase S,
    // one barrier ago; phase R reads only sortedId/AoS.
    float (*part)[4][64] = reinterpret_cast<float (*)[4][64]>(survKeys);
    part[wave][0][lane] = accr;
    part[wave][1][lane] = accg;
    part[wave][2][lane] = accb;
    part[wave][3][lane] = T;
    __syncthreads();
    if (wave == 0) {
        float R = part[0][0][lane], G = part[0][1][lane], Bc = part[0][2][lane];
        float Tt = part[0][3][lane];
#pragma unroll
        for (int s = 1; s < NSEG; ++s) {
            R  = fmaf(Tt, part[s][0][lane], R);
            G  = fmaf(Tt, part[s][1][lane], G);
            Bc = fmaf(Tt, part[s][2][lane], Bc);
            Tt *= part[s][3][lane];
        }
        const int pix = (tile_y + (lane >> 3)) * IMG_W + tile_x + (lane & 7);
        out[pix]            = fmaf(Tt, bgp[0], R);
        out[pix + NPIX]     = fmaf(Tt, bgp[1], G);
        out[pix + 2 * NPIX] = fmaf(Tt, bgp[2], Bc);
    }
}

// ---------------------------------------------------------------------------
extern "C" void kernel_launch(void* const* d_in, const int* in_sizes, int n_in,
                              void* d_out, int out_size, void* d_ws, size_t ws_size,
                              hipStream_t stream) {
    const float* means  = (const float*)d_in[0];  // (N,3)
    const float* colors = (const float*)d_in[1];  // (N,3)
    const float* opac   = (const float*)d_in[2];  // (N,1)
    const float* cov3   = (const float*)d_in[3];  // (N,6)
    const float* bg     = (const float*)d_in[4];  // (3,)
    float* out = (float*)d_out;  // img (3*128*128) then radii (2048) as float

    fused_kernel<<<256, 1024, 0, stream>>>(means, colors, opac, cov3, bg,
                                           out, out + 3 * NPIX);
}